// Round 6
// baseline (719.559 us; speedup 1.0000x reference)
//
#include <hip/hip_runtime.h>
#include <math.h>

#define NN 4096
#define NE 131072
#define DIM 256
#define NHEAD 8
#define HD 32

typedef __attribute__((ext_vector_type(8))) short short8v;
typedef __attribute__((ext_vector_type(4))) float f32x4;
#define MFMA16(a, b, c) __builtin_amdgcn_mfma_f32_16x16x32_bf16(a, b, c, 0, 0, 0)

__device__ __forceinline__ float elu_f(float v){ return v > 0.f ? v : expm1f(v); }
__device__ __forceinline__ float gelu_f(float v){
  const float c = 0.7978845608028654f;
  float t = tanhf(c * (v + 0.044715f * v * v * v));
  return 0.5f * v * (1.f + t);
}
__device__ __forceinline__ unsigned short f2bf(float f) {
  unsigned int u = __builtin_bit_cast(unsigned int, f);
  u += 0x7FFFu + ((u >> 16) & 1u);
  return (unsigned short)(u >> 16);
}
__device__ __forceinline__ unsigned int pk2(float a, float b) {
  return (unsigned int)f2bf(a) | ((unsigned int)f2bf(b) << 16);
}

// ---------------- CSR build ----------------
__global__ void zero_counts(int* __restrict__ counts) {
  int i = blockIdx.x * 256 + threadIdx.x;
  if (i < NN) counts[i] = 0;
}

__global__ void count_edges(const int* __restrict__ ei, int* __restrict__ counts) {
  int e = blockIdx.x * 256 + threadIdx.x;
  if (e < NE) atomicAdd(&counts[ei[NE + e]], 1);
}

__global__ __launch_bounds__(1024) void scan_offsets(const int* __restrict__ counts,
                                                     int* __restrict__ offs,
                                                     int* __restrict__ cursor) {
  __shared__ int tmp[1024];
  int t = threadIdx.x;
  int base = t * 4;
  int c0 = counts[base], c1 = counts[base+1], c2 = counts[base+2], c3 = counts[base+3];
  int tsum = c0 + c1 + c2 + c3;
  tmp[t] = tsum;
  __syncthreads();
  for (int d = 1; d < 1024; d <<= 1) {
    int v = (t >= d) ? tmp[t - d] : 0;
    __syncthreads();
    tmp[t] += v;
    __syncthreads();
  }
  int excl = tmp[t] - tsum;
  offs[base]   = excl;           cursor[base]   = excl;
  offs[base+1] = excl + c0;      cursor[base+1] = excl + c0;
  offs[base+2] = excl + c0 + c1; cursor[base+2] = excl + c0 + c1;
  offs[base+3] = excl + c0 + c1 + c2; cursor[base+3] = excl + c0 + c1 + c2;
  if (t == 1023) offs[NN] = tmp[1023];
}

__global__ void scatter_edges(const int* __restrict__ ei, int* __restrict__ cursor,
                              int* __restrict__ esrc) {
  int e = blockIdx.x * 256 + threadIdx.x;
  if (e < NE) {
    int d = ei[NE + e];
    int pos = atomicAdd(&cursor[d], 1);
    esrc[pos] = ei[e];
  }
}

// block per node: aggb[n][c] = bf16( (1+eps)*x[n][c] + sum_{e} x[src_e][c] )
__global__ __launch_bounds__(256) void gin_agg(const int* __restrict__ offs,
                                               const int* __restrict__ esrc,
                                               const float* __restrict__ x,
                                               const float* __restrict__ eps_p, int l,
                                               unsigned short* __restrict__ aggb) {
  int n = blockIdx.x, c = threadIdx.x;
  int e0 = offs[n], e1 = offs[n + 1];
  float acc = 0.f;
  for (int e = e0; e < e1; e++) acc += x[(size_t)esrc[e] * DIM + c];
  float eps = eps_p[l];
  aggb[(size_t)n * DIM + c] = f2bf((1.f + eps) * x[(size_t)n * DIM + c] + acc);
}

// ---------------- bf16 MFMA GEMM: C = act(A @ W^T + bias) ----------------
template<int ACT, int WF32, int WBF16, int QSCALE>
__global__ __launch_bounds__(256) void gemm_mfma(
    const unsigned short* __restrict__ A, const unsigned short* __restrict__ W,
    const float* __restrict__ bias, float* __restrict__ Cf,
    unsigned short* __restrict__ Cb, int M, int N, int K)
{
  __shared__ __align__(16) unsigned short As[64][40];
  __shared__ __align__(16) unsigned short Ws[64][40];
  int t = threadIdx.x;
  int w = t >> 6, lane = t & 63, lo = lane & 15, g = lane >> 4;
  int wr = w >> 1, wc = w & 1;
  int bn = blockIdx.x * 64, bm = blockIdx.y * 64;
  int srow = t >> 2, skk = (t & 3) << 3;
  const unsigned short* ap = A + (size_t)(bm + srow) * K + skk;
  const unsigned short* wp = W + (size_t)(bn + srow) * K + skk;

  f32x4 acc[2][2] = {{{0.f,0.f,0.f,0.f},{0.f,0.f,0.f,0.f}},
                     {{0.f,0.f,0.f,0.f},{0.f,0.f,0.f,0.f}}};

  for (int k0 = 0; k0 < K; k0 += 32) {
    *(short8v*)&As[srow][skk] = *(const short8v*)(ap + k0);
    *(short8v*)&Ws[srow][skk] = *(const short8v*)(wp + k0);
    __syncthreads();
    short8v a0 = *(const short8v*)&As[wr * 32 + lo][8 * g];
    short8v a1 = *(const short8v*)&As[wr * 32 + 16 + lo][8 * g];
    short8v b0 = *(const short8v*)&Ws[wc * 32 + lo][8 * g];
    short8v b1 = *(const short8v*)&Ws[wc * 32 + 16 + lo][8 * g];
    acc[0][0] = MFMA16(a0, b0, acc[0][0]);
    acc[0][1] = MFMA16(a0, b1, acc[0][1]);
    acc[1][0] = MFMA16(a1, b0, acc[1][0]);
    acc[1][1] = MFMA16(a1, b1, acc[1][1]);
    __syncthreads();
  }

  #pragma unroll
  for (int mi = 0; mi < 2; mi++) {
    #pragma unroll
    for (int ni = 0; ni < 2; ni++) {
      #pragma unroll
      for (int r = 0; r < 4; r++) {
        int row = bm + wr * 32 + mi * 16 + 4 * g + r;
        int col = bn + wc * 32 + ni * 16 + lo;
        float v = acc[mi][ni][r] + bias[col];
        if (ACT == 1) v = elu_f(v);
        if (ACT == 2) v = gelu_f(v);
        if (QSCALE) { if (col < 256) v *= 0.17677669529663687f; }
        if (WF32) Cf[(size_t)row * N + col] = v;
        if (WBF16) Cb[(size_t)row * N + col] = f2bf(v);
      }
    }
  }
}

// ---------------- LayerNorm(+act) + residual add; also emits bf16 copy ----------------
template<int ACT>
__global__ __launch_bounds__(256) void ln_act_add(const float* __restrict__ in,
                                                  const float* __restrict__ g,
                                                  const float* __restrict__ b,
                                                  float* __restrict__ x,
                                                  unsigned short* __restrict__ xb) {
  int rowb = blockIdx.x;
  int c = threadIdx.x;
  float v = in[(size_t)rowb * DIM + c];
  float s = v, s2 = v * v;
  #pragma unroll
  for (int off = 32; off >= 1; off >>= 1) {
    s  += __shfl_xor(s,  off, 64);
    s2 += __shfl_xor(s2, off, 64);
  }
  __shared__ float ws1[4], ws2[4];
  int w = threadIdx.x >> 6, lane = threadIdx.x & 63;
  if (lane == 0) { ws1[w] = s; ws2[w] = s2; }
  __syncthreads();
  s  = ws1[0] + ws1[1] + ws1[2] + ws1[3];
  s2 = ws2[0] + ws2[1] + ws2[2] + ws2[3];
  float mean = s * (1.f / DIM);
  float var = s2 * (1.f / DIM) - mean * mean;
  float r = rsqrtf(var + 1e-5f);
  float o = (v - mean) * r * g[c] + b[c];
  if (ACT == 1) o = elu_f(o);
  float nx = x[(size_t)rowb * DIM + c] + o;
  x[(size_t)rowb * DIM + c] = nx;
  xb[(size_t)rowb * DIM + c] = f2bf(nx);
}

// ---------------- V transpose ----------------
__global__ __launch_bounds__(256) void vt_transpose(const unsigned short* __restrict__ tbb,
                                                    unsigned short* __restrict__ VT) {
  __shared__ unsigned short lds[128][33];
  int h = blockIdx.y;
  int nb = blockIdx.x * 128;
  int tid = threadIdx.x;
  int r8 = tid >> 5, d = tid & 31;
  #pragma unroll
  for (int i = 0; i < 16; i++) {
    int n = i * 8 + r8;
    lds[n][d] = tbb[(size_t)(nb + n) * 768 + 512 + h * 32 + d];
  }
  __syncthreads();
  int dd = tid >> 7, j = tid & 127;
  #pragma unroll
  for (int i = 0; i < 16; i++) {
    int d2 = i * 2 + dd;
    VT[((size_t)h * 32 + d2) * 4096 + nb + j] = lds[j][d2];
  }
}

// ---------------- MFMA flash attention v3: swapped QK^T, in-register softmax ----------------
// Per wave: 16 q-rows, one head. S^T = mfma(A=K,B=Q) puts all k-scores for q=lane&15
// in-lane. PV contraction-slot order is permuted (sigma(8g+r) = r<4 ? 4g+r : 12+4g+r)
// so P needs NO cross-lane exchange; V^T columns are loaded in matching order.
__global__ __launch_bounds__(256) void attn_mfma_split(
    const unsigned short* __restrict__ qkvb, const unsigned short* __restrict__ VT,
    float* __restrict__ po, float* __restrict__ ml, int kspan) {
  int tid = threadIdx.x;
  int w = tid >> 6, lane = tid & 63;
  int lo = lane & 15, g = lane >> 4;
  int h = blockIdx.y;
  int s = blockIdx.z;
  int qb = blockIdx.x * 64 + w * 16;
  int k_lo = s * kspan, k_hi = k_lo + kspan;

  // Q B-frag: col=q=qb+lo, contraction d = 8g..8g+7
  short8v qf = *(const short8v*)(qkvb + (size_t)(qb + lo) * 768 + h * 32 + 8 * g);

  f32x4 acc0 = {0.f, 0.f, 0.f, 0.f};   // O^T[d=4g+r][q=lo]
  f32x4 acc1 = {0.f, 0.f, 0.f, 0.f};   // O^T[d=16+4g+r][q=lo]
  float m = -1e30f, l = 0.f;

  const unsigned short* Kb = qkvb + 256 + h * 32 + 8 * g;       // + k*768
  const unsigned short* V0 = VT + ((size_t)(h * 32 + lo)) * 4096;       // d = lo
  const unsigned short* V1 = VT + ((size_t)(h * 32 + 16 + lo)) * 4096;  // d = lo+16
  const f32x4 zf = {0.f, 0.f, 0.f, 0.f};

  for (int kb = k_lo; kb < k_hi; kb += 32) {
    // K A-frags: rows k = kb+lo, kb+16+lo; contraction d = 8g..8g+7
    short8v kA0 = *(const short8v*)(Kb + (size_t)(kb + lo) * 768);
    short8v kA1 = *(const short8v*)(Kb + (size_t)(kb + 16 + lo) * 768);
    f32x4 s0 = MFMA16(kA0, qf, zf);   // S[k=4g+r][q=lo]
    f32x4 s1 = MFMA16(kA1, qf, zf);   // S[k=16+4g+r][q=lo]

    // tile max for q=lo (in-lane 8, then sync across the 4 g-lanes)
    float t = fmaxf(fmaxf(fmaxf(s0[0], s0[1]), fmaxf(s0[2], s0[3])),
                    fmaxf(fmaxf(s1[0], s1[1]), fmaxf(s1[2], s1[3])));
    t = fmaxf(t, __shfl_xor(t, 16, 64));
    t = fmaxf(t, __shfl_xor(t, 32, 64));
    if (!__all(t <= m)) {
      float nm = fmaxf(m, t);
      float f = __expf(m - nm);
      m = nm;
      l *= f;
      #pragma unroll
      for (int r = 0; r < 4; r++) { acc0[r] *= f; acc1[r] *= f; }
    }
    float p0 = __expf(s0[0] - m), p1 = __expf(s0[1] - m);
    float p2 = __expf(s0[2] - m), p3 = __expf(s0[3] - m);
    float p4 = __expf(s1[0] - m), p5 = __expf(s1[1] - m);
    float p6 = __expf(s1[2] - m), p7 = __expf(s1[3] - m);
    l += ((p0 + p1) + (p2 + p3)) + ((p4 + p5) + (p6 + p7));

    // P B-frag in permuted slot order (all lane-local)
    unsigned u0 = pk2(p0, p1), u1 = pk2(p2, p3), u2 = pk2(p4, p5), u3 = pk2(p6, p7);
    uint4 uu = {u0, u1, u2, u3};
    short8v pb = __builtin_bit_cast(short8v, uu);

    // V^T A-frags with matching permuted columns: k = kb + {4g..4g+3, 16+4g..16+4g+3}
    short4 vl0 = *(const short4*)(V0 + kb + 4 * g);
    short4 vh0 = *(const short4*)(V0 + kb + 16 + 4 * g);
    short4 vl1 = *(const short4*)(V1 + kb + 4 * g);
    short4 vh1 = *(const short4*)(V1 + kb + 16 + 4 * g);
    short8v vf0 = {vl0.x, vl0.y, vl0.z, vl0.w, vh0.x, vh0.y, vh0.z, vh0.w};
    short8v vf1 = {vl1.x, vl1.y, vl1.z, vl1.w, vh1.x, vh1.y, vh1.z, vh1.w};

    acc0 = MFMA16(vf0, pb, acc0);
    acc1 = MFMA16(vf1, pb, acc1);
  }

  // finalize l across the 4 g-lanes (m already synced)
  l += __shfl_xor(l, 16, 64);
  l += __shfl_xor(l, 32, 64);

  int q = qb + lo;
  float* pr = po + ((size_t)s * NN + q) * DIM + h * 32 + 4 * g;
  *(f32x4*)pr = acc0;
  *(f32x4*)(pr + 16) = acc1;
  if (g == 0) {
    float2* mlp = (float2*)(ml + (((size_t)s * NN + q) * NHEAD + h) * 2);
    *mlp = float2{m, l};
  }
}

// combine k-splits: attb[q][c] = sum_s e^{m_s-M} po_s / sum_s e^{m_s-M} l_s
__global__ __launch_bounds__(256) void attn_merge(const float* __restrict__ po,
                                                  const float* __restrict__ ml,
                                                  unsigned short* __restrict__ attb, int S) {
  int q = blockIdx.x;
  int c = threadIdx.x;
  int h = c >> 5;
  float M = -1e30f;
  for (int s = 0; s < S; s++)
    M = fmaxf(M, ml[(((size_t)s * NN + q) * NHEAD + h) * 2]);
  float L = 0.f, O = 0.f;
  for (int s = 0; s < S; s++) {
    const float* mlp = ml + (((size_t)s * NN + q) * NHEAD + h) * 2;
    float e = __expf(mlp[0] - M);
    L += e * mlp[1];
    O += e * po[((size_t)s * NN + q) * DIM + c];
  }
  attb[(size_t)q * DIM + c] = f2bf(O / L);
}

// ---------------- weight conversion ----------------
#define WO0 0
#define WO1 131072
#define WO2 262144
#define WO3 655360
#define WO4 786432
#define WO5 1048576
#define WO6 1310720
#define WTOT 1343488
__global__ __launch_bounds__(256) void wconv(const float* __restrict__ s0, const float* __restrict__ s1,
                                             const float* __restrict__ s2, const float* __restrict__ s3,
                                             const float* __restrict__ s4, const float* __restrict__ s5,
                                             const float* __restrict__ s6, unsigned short* __restrict__ dst) {
  int i4 = (blockIdx.x * 256 + threadIdx.x) * 4;
  if (i4 >= WTOT) return;
  const float* src; int loc;
  if      (i4 < WO1) { src = s0; loc = i4 - WO0; }
  else if (i4 < WO2) { src = s1; loc = i4 - WO1; }
  else if (i4 < WO3) { src = s2; loc = i4 - WO2; }
  else if (i4 < WO4) { src = s3; loc = i4 - WO3; }
  else if (i4 < WO5) { src = s4; loc = i4 - WO4; }
  else if (i4 < WO6) { src = s5; loc = i4 - WO5; }
  else               { src = s6; loc = i4 - WO6; }
  float4 v = *(const float4*)(src + loc);
  ushort4 o;
  o.x = f2bf(v.x); o.y = f2bf(v.y); o.z = f2bf(v.z); o.w = f2bf(v.w);
  *(ushort4*)(dst + i4) = o;
}

__global__ __launch_bounds__(256) void pad72_96(const float* __restrict__ src,
                                                unsigned short* __restrict__ dst, int total) {
  int idx = blockIdx.x * 256 + threadIdx.x;
  if (idx >= total) return;
  int row = idx / 96, col = idx - row * 96;
  dst[idx] = (col < 72) ? f2bf(src[row * 72 + col]) : (unsigned short)0;
}

// ---------------- tiny head ----------------
__global__ void head2_kernel(const float* __restrict__ e, const float* __restrict__ w,
                             const float* __restrict__ b, float* __restrict__ out) {
  int idx = blockIdx.x * 256 + threadIdx.x;
  if (idx >= NN * 5) return;
  int rowi = idx / 5, col = idx % 5;
  float s = b[col];
  const float* ep = e + (size_t)rowi * 128;
  const float* wp = w + (size_t)col * 128;
  #pragma unroll 16
  for (int k = 0; k < 128; k++) s += ep[k] * wp[k];
  out[idx] = s;
}

extern "C" void kernel_launch(void* const* d_in, const int* in_sizes, int n_in,
                              void* d_out, int out_size, void* d_ws, size_t ws_size,
                              hipStream_t stream) {
  const float* x_in   = (const float*)d_in[0];
  const int*   ei     = (const int*)  d_in[1];
  const float* in_w   = (const float*)d_in[2];
  const float* in_b   = (const float*)d_in[3];
  const float* head_w1= (const float*)d_in[4];
  const float* head_b1= (const float*)d_in[5];
  const float* head_w2= (const float*)d_in[6];
  const float* head_b2= (const float*)d_in[7];
  const float* mlp_w1 = (const float*)d_in[8];
  const float* mlp_b1 = (const float*)d_in[9];
  const float* mlp_w2 = (const float*)d_in[10];
  const float* mlp_b2 = (const float*)d_in[11];
  const float* gin_eps= (const float*)d_in[12];
  const float* ln1_g  = (const float*)d_in[13];
  const float* ln1_b  = (const float*)d_in[14];
  const float* attn_in_w = (const float*)d_in[15];
  const float* attn_in_b = (const float*)d_in[16];
  const float* attn_out_w= (const float*)d_in[17];
  const float* attn_out_b= (const float*)d_in[18];
  const float* ln2_g  = (const float*)d_in[19];
  const float* ln2_b  = (const float*)d_in[20];
  const float* ffn_w1 = (const float*)d_in[21];
  const float* ffn_b1 = (const float*)d_in[22];
  const float* ffn_w2 = (const float*)d_in[23];
  const float* ffn_b2 = (const float*)d_in[24];
  const float* ln3_g  = (const float*)d_in[25];
  const float* ln3_b  = (const float*)d_in[26];

  float* ws = (float*)d_ws;
  float* x    = ws;                              // [NN,256] f32
  float* t2   = x  + (size_t)NN * DIM;           // [NN,256] f32
  float* he   = t2 + (size_t)NN * DIM;           // [NN,128] f32
  unsigned short* xb   = (unsigned short*)(he + (size_t)NN * 128);
  unsigned short* tbb  = xb   + (size_t)NN * DIM;       // [NN,768] bf16
  unsigned short* aggb = tbb  + (size_t)NN * 768;       // [NN,256] bf16
  unsigned short* attb = aggb + (size_t)NN * DIM;       // [NN,256] bf16
  unsigned short* VT   = attb + (size_t)NN * DIM;       // [256][NN] bf16
  unsigned short* xinb = VT   + (size_t)NN * DIM;       // [NN][96] bf16
  unsigned short* inwb = xinb + (size_t)NN * 96;        // [256][96] bf16
  unsigned short* warena = inwb + 256 * 96;             // WTOT bf16
  int* counts = (int*)(warena + WTOT);
  int* offs   = counts + NN;       // NN+1
  int* cursor = offs + NN + 1;
  int* esrc   = cursor + NN;       // NE
  float* po   = (float*)(esrc + NE);   // [S][NN][DIM] f32
  size_t used_f = (size_t)(po - ws);
  int S = 1;
  for (int cand = 4; cand >= 2; cand >>= 1) {
    size_t need = (used_f + (size_t)cand * NN * DIM + (size_t)cand * NN * NHEAD * 2) * 4;
    if (ws_size >= need) { S = cand; break; }
  }
  float* ml = po + (size_t)S * NN * DIM;
  int kspan = NN / S;

  const unsigned short* w_mlp1 = warena + WO0;
  const unsigned short* w_mlp2 = warena + WO1;
  const unsigned short* w_qkv  = warena + WO2;
  const unsigned short* w_aout = warena + WO3;
  const unsigned short* w_ffn1 = warena + WO4;
  const unsigned short* w_ffn2 = warena + WO5;
  const unsigned short* w_h1   = warena + WO6;

  // CSR build
  zero_counts<<<16, 256, 0, stream>>>(counts);
  count_edges<<<NE / 256, 256, 0, stream>>>(ei, counts);
  scan_offsets<<<1, 1024, 0, stream>>>(counts, offs, cursor);
  scatter_edges<<<NE / 256, 256, 0, stream>>>(ei, cursor, esrc);

  // weight + input conversions
  wconv<<<1312, 256, 0, stream>>>(mlp_w1, mlp_w2, attn_in_w, attn_out_w, ffn_w1, ffn_w2,
                                  head_w1, warena);
  pad72_96<<<(NN * 96 + 255) / 256, 256, 0, stream>>>(x_in, xinb, NN * 96);
  pad72_96<<<(256 * 96 + 255) / 256, 256, 0, stream>>>(in_w, inwb, 256 * 96);

  // input projection
  gemm_mfma<1,1,1,0><<<dim3(DIM/64, NN/64), 256, 0, stream>>>(xinb, inwb, in_b, x, xb,
                                                              NN, DIM, 96);

  for (int l = 0; l < 2; l++) {
    // GIN
    gin_agg<<<NN, 256, 0, stream>>>(offs, esrc, x, gin_eps, l, aggb);
    gemm_mfma<1,0,1,0><<<dim3(4, 64), 256, 0, stream>>>(aggb, w_mlp1 + (size_t)l*65536,
                                                        mlp_b1 + l*DIM, nullptr, tbb,
                                                        NN, DIM, DIM);
    gemm_mfma<0,1,0,0><<<dim3(4, 64), 256, 0, stream>>>(tbb, w_mlp2 + (size_t)l*65536,
                                                        mlp_b2 + l*DIM, t2, nullptr,
                                                        NN, DIM, DIM);
    ln_act_add<1><<<NN, 256, 0, stream>>>(t2, ln1_g + l*DIM, ln1_b + l*DIM, x, xb);

    // attention
    gemm_mfma<0,0,1,1><<<dim3(12, 64), 256, 0, stream>>>(xb, w_qkv + (size_t)l*196608,
                                                         attn_in_b + l*768, nullptr, tbb,
                                                         NN, 768, DIM);
    vt_transpose<<<dim3(32, 8), 256, 0, stream>>>(tbb, VT);
    attn_mfma_split<<<dim3(64, NHEAD, S), 256, 0, stream>>>(tbb, VT, po, ml, kspan);
    attn_merge<<<NN, 256, 0, stream>>>(po, ml, attb, S);
    gemm_mfma<0,1,0,0><<<dim3(4, 64), 256, 0, stream>>>(attb, w_aout + (size_t)l*65536,
                                                        attn_out_b + l*DIM, t2, nullptr,
                                                        NN, DIM, DIM);
    ln_act_add<0><<<NN, 256, 0, stream>>>(t2, ln2_g + l*DIM, ln2_b + l*DIM, x, xb);

    // FFN
    gemm_mfma<2,0,1,0><<<dim3(8, 64), 256, 0, stream>>>(xb, w_ffn1 + (size_t)l*131072,
                                                        ffn_b1 + l*512, nullptr, tbb,
                                                        NN, 512, DIM);
    gemm_mfma<0,1,0,0><<<dim3(4, 64), 256, 0, stream>>>(tbb, w_ffn2 + (size_t)l*131072,
                                                        ffn_b2 + l*DIM, t2, nullptr,
                                                        NN, DIM, 512);
    ln_act_add<0><<<NN, 256, 0, stream>>>(t2, ln3_g + l*DIM, ln3_b + l*DIM, x, xb);
  }

  // head
  gemm_mfma<1,1,0,0><<<dim3(2, 64), 256, 0, stream>>>(xb, w_h1, head_b1, he, nullptr,
                                                      NN, 128, DIM);
  head2_kernel<<<(NN * 5 + 255) / 256, 256, 0, stream>>>(he, head_w2, head_b2, (float*)d_out);
}

// Round 7
// 620.082 us; speedup vs baseline: 1.1604x; 1.1604x over previous
//
#include <hip/hip_runtime.h>
#include <math.h>

#define NN 4096
#define NE 131072
#define DIM 256
#define NHEAD 8
#define HD 32

typedef __attribute__((ext_vector_type(8))) short short8v;
typedef __attribute__((ext_vector_type(4))) float f32x4;
#define MFMA16(a, b, c) __builtin_amdgcn_mfma_f32_16x16x32_bf16(a, b, c, 0, 0, 0)

__device__ __forceinline__ float elu_f(float v){ return v > 0.f ? v : expm1f(v); }
__device__ __forceinline__ float gelu_f(float v){
  const float c = 0.7978845608028654f;
  float t = tanhf(c * (v + 0.044715f * v * v * v));
  return 0.5f * v * (1.f + t);
}
__device__ __forceinline__ unsigned short f2bf(float f) {
  unsigned int u = __builtin_bit_cast(unsigned int, f);
  u += 0x7FFFu + ((u >> 16) & 1u);
  return (unsigned short)(u >> 16);
}
__device__ __forceinline__ unsigned int pk2(float a, float b) {
  return (unsigned int)f2bf(a) | ((unsigned int)f2bf(b) << 16);
}

// ---------------- CSR build ----------------
__global__ void zero_counts(int* __restrict__ counts) {
  int i = blockIdx.x * 256 + threadIdx.x;
  if (i < NN) counts[i] = 0;
}

__global__ void count_edges(const int* __restrict__ ei, int* __restrict__ counts) {
  int e = blockIdx.x * 256 + threadIdx.x;
  if (e < NE) atomicAdd(&counts[ei[NE + e]], 1);
}

__global__ __launch_bounds__(1024) void scan_offsets(const int* __restrict__ counts,
                                                     int* __restrict__ offs,
                                                     int* __restrict__ cursor) {
  __shared__ int tmp[1024];
  int t = threadIdx.x;
  int base = t * 4;
  int c0 = counts[base], c1 = counts[base+1], c2 = counts[base+2], c3 = counts[base+3];
  int tsum = c0 + c1 + c2 + c3;
  tmp[t] = tsum;
  __syncthreads();
  for (int d = 1; d < 1024; d <<= 1) {
    int v = (t >= d) ? tmp[t - d] : 0;
    __syncthreads();
    tmp[t] += v;
    __syncthreads();
  }
  int excl = tmp[t] - tsum;
  offs[base]   = excl;           cursor[base]   = excl;
  offs[base+1] = excl + c0;      cursor[base+1] = excl + c0;
  offs[base+2] = excl + c0 + c1; cursor[base+2] = excl + c0 + c1;
  offs[base+3] = excl + c0 + c1 + c2; cursor[base+3] = excl + c0 + c1 + c2;
  if (t == 1023) offs[NN] = tmp[1023];
}

__global__ void scatter_edges(const int* __restrict__ ei, int* __restrict__ cursor,
                              int* __restrict__ esrc) {
  int e = blockIdx.x * 256 + threadIdx.x;
  if (e < NE) {
    int d = ei[NE + e];
    int pos = atomicAdd(&cursor[d], 1);
    esrc[pos] = ei[e];
  }
}

// block per node: aggb[n][c] = bf16( (1+eps)*x[n][c] + sum_{e} x[src_e][c] )
__global__ __launch_bounds__(256) void gin_agg(const int* __restrict__ offs,
                                               const int* __restrict__ esrc,
                                               const float* __restrict__ x,
                                               const float* __restrict__ eps_p, int l,
                                               unsigned short* __restrict__ aggb) {
  int n = blockIdx.x, c = threadIdx.x;
  int e0 = offs[n], e1 = offs[n + 1];
  float acc = 0.f;
  for (int e = e0; e < e1; e++) acc += x[(size_t)esrc[e] * DIM + c];
  float eps = eps_p[l];
  aggb[(size_t)n * DIM + c] = f2bf((1.f + eps) * x[(size_t)n * DIM + c] + acc);
}

// ---------------- bf16 MFMA GEMM: C = act(A @ W^T + bias) ----------------
template<int ACT, int WF32, int WBF16, int QSCALE>
__global__ __launch_bounds__(256) void gemm_mfma(
    const unsigned short* __restrict__ A, const unsigned short* __restrict__ W,
    const float* __restrict__ bias, float* __restrict__ Cf,
    unsigned short* __restrict__ Cb, int M, int N, int K)
{
  __shared__ __align__(16) unsigned short As[64][40];
  __shared__ __align__(16) unsigned short Ws[64][40];
  int t = threadIdx.x;
  int w = t >> 6, lane = t & 63, lo = lane & 15, g = lane >> 4;
  int wr = w >> 1, wc = w & 1;
  int bn = blockIdx.x * 64, bm = blockIdx.y * 64;
  int srow = t >> 2, skk = (t & 3) << 3;
  const unsigned short* ap = A + (size_t)(bm + srow) * K + skk;
  const unsigned short* wp = W + (size_t)(bn + srow) * K + skk;

  f32x4 acc[2][2] = {{{0.f,0.f,0.f,0.f},{0.f,0.f,0.f,0.f}},
                     {{0.f,0.f,0.f,0.f},{0.f,0.f,0.f,0.f}}};

  for (int k0 = 0; k0 < K; k0 += 32) {
    *(short8v*)&As[srow][skk] = *(const short8v*)(ap + k0);
    *(short8v*)&Ws[srow][skk] = *(const short8v*)(wp + k0);
    __syncthreads();
    short8v a0 = *(const short8v*)&As[wr * 32 + lo][8 * g];
    short8v a1 = *(const short8v*)&As[wr * 32 + 16 + lo][8 * g];
    short8v b0 = *(const short8v*)&Ws[wc * 32 + lo][8 * g];
    short8v b1 = *(const short8v*)&Ws[wc * 32 + 16 + lo][8 * g];
    acc[0][0] = MFMA16(a0, b0, acc[0][0]);
    acc[0][1] = MFMA16(a0, b1, acc[0][1]);
    acc[1][0] = MFMA16(a1, b0, acc[1][0]);
    acc[1][1] = MFMA16(a1, b1, acc[1][1]);
    __syncthreads();
  }

  #pragma unroll
  for (int mi = 0; mi < 2; mi++) {
    #pragma unroll
    for (int ni = 0; ni < 2; ni++) {
      #pragma unroll
      for (int r = 0; r < 4; r++) {
        int row = bm + wr * 32 + mi * 16 + 4 * g + r;
        int col = bn + wc * 32 + ni * 16 + lo;
        float v = acc[mi][ni][r] + bias[col];
        if (ACT == 1) v = elu_f(v);
        if (ACT == 2) v = gelu_f(v);
        if (QSCALE) { if (col < 256) v *= 0.17677669529663687f; }
        if (WF32) Cf[(size_t)row * N + col] = v;
        if (WBF16) Cb[(size_t)row * N + col] = f2bf(v);
      }
    }
  }
}

// ---------------- LayerNorm(+act) + residual add; also emits bf16 copy ----------------
template<int ACT>
__global__ __launch_bounds__(256) void ln_act_add(const float* __restrict__ in,
                                                  const float* __restrict__ g,
                                                  const float* __restrict__ b,
                                                  float* __restrict__ x,
                                                  unsigned short* __restrict__ xb) {
  int rowb = blockIdx.x;
  int c = threadIdx.x;
  float v = in[(size_t)rowb * DIM + c];
  float s = v, s2 = v * v;
  #pragma unroll
  for (int off = 32; off >= 1; off >>= 1) {
    s  += __shfl_xor(s,  off, 64);
    s2 += __shfl_xor(s2, off, 64);
  }
  __shared__ float ws1[4], ws2[4];
  int w = threadIdx.x >> 6, lane = threadIdx.x & 63;
  if (lane == 0) { ws1[w] = s; ws2[w] = s2; }
  __syncthreads();
  s  = ws1[0] + ws1[1] + ws1[2] + ws1[3];
  s2 = ws2[0] + ws2[1] + ws2[2] + ws2[3];
  float mean = s * (1.f / DIM);
  float var = s2 * (1.f / DIM) - mean * mean;
  float r = rsqrtf(var + 1e-5f);
  float o = (v - mean) * r * g[c] + b[c];
  if (ACT == 1) o = elu_f(o);
  float nx = x[(size_t)rowb * DIM + c] + o;
  x[(size_t)rowb * DIM + c] = nx;
  xb[(size_t)rowb * DIM + c] = f2bf(nx);
}

// ---------------- V transpose ----------------
__global__ __launch_bounds__(256) void vt_transpose(const unsigned short* __restrict__ tbb,
                                                    unsigned short* __restrict__ VT) {
  __shared__ unsigned short lds[128][33];
  int h = blockIdx.y;
  int nb = blockIdx.x * 128;
  int tid = threadIdx.x;
  int r8 = tid >> 5, d = tid & 31;
  #pragma unroll
  for (int i = 0; i < 16; i++) {
    int n = i * 8 + r8;
    lds[n][d] = tbb[(size_t)(nb + n) * 768 + 512 + h * 32 + d];
  }
  __syncthreads();
  int dd = tid >> 7, j = tid & 127;
  #pragma unroll
  for (int i = 0; i < 16; i++) {
    int d2 = i * 2 + dd;
    VT[((size_t)h * 32 + d2) * 4096 + nb + j] = lds[j][d2];
  }
}

// ---------------- MFMA flash attention v4: swapped QK^T, in-reg softmax, 2-deep pipeline --
// Per wave: 16 q-rows, one head. 64-k per STEP (4 S-MFMA + 4 PV-MFMA + 16 exp).
// Register double-buffer: loads for tile t+1 issued before compute of tile t.
#define LK(kb, A0, A1, A2, A3)                                      \
  A0 = *(const short8v*)(Kp + (size_t)((kb) + lo) * 768);           \
  A1 = *(const short8v*)(Kp + (size_t)((kb) + 16 + lo) * 768);      \
  A2 = *(const short8v*)(Kp + (size_t)((kb) + 32 + lo) * 768);      \
  A3 = *(const short8v*)(Kp + (size_t)((kb) + 48 + lo) * 768);

#define LV(kb, W0, W1, W2, W3, X0, X1, X2, X3)                      \
  W0 = *(const short4*)(Vp0 + (kb));                                \
  W1 = *(const short4*)(Vp0 + (kb) + 16);                           \
  W2 = *(const short4*)(Vp0 + (kb) + 32);                           \
  W3 = *(const short4*)(Vp0 + (kb) + 48);                           \
  X0 = *(const short4*)(Vp1 + (kb));                                \
  X1 = *(const short4*)(Vp1 + (kb) + 16);                           \
  X2 = *(const short4*)(Vp1 + (kb) + 32);                           \
  X3 = *(const short4*)(Vp1 + (kb) + 48);

#define STEP(A0, A1, A2, A3, W0, W1, W2, W3, X0, X1, X2, X3) do {   \
  f32x4 s0_ = MFMA16(A0, qf, zf);                                   \
  f32x4 s1_ = MFMA16(A1, qf, zf);                                   \
  f32x4 s2_ = MFMA16(A2, qf, zf);                                   \
  f32x4 s3_ = MFMA16(A3, qf, zf);                                   \
  float ta_ = fmaxf(fmaxf(fmaxf(s0_[0],s0_[1]), fmaxf(s0_[2],s0_[3])),   \
                    fmaxf(fmaxf(s1_[0],s1_[1]), fmaxf(s1_[2],s1_[3])));  \
  float tb_ = fmaxf(fmaxf(fmaxf(s2_[0],s2_[1]), fmaxf(s2_[2],s2_[3])),   \
                    fmaxf(fmaxf(s3_[0],s3_[1]), fmaxf(s3_[2],s3_[3])));  \
  float t_ = fmaxf(ta_, tb_);                                       \
  t_ = fmaxf(t_, __shfl_xor(t_, 16, 64));                           \
  t_ = fmaxf(t_, __shfl_xor(t_, 32, 64));                           \
  if (!__all(t_ <= m)) {                                            \
    float nm_ = fmaxf(m, t_);                                       \
    float f_ = __expf(m - nm_);                                     \
    m = nm_; l *= f_;                                               \
    acc0[0]*=f_; acc0[1]*=f_; acc0[2]*=f_; acc0[3]*=f_;             \
    acc1[0]*=f_; acc1[1]*=f_; acc1[2]*=f_; acc1[3]*=f_;             \
  }                                                                 \
  float p0_=__expf(s0_[0]-m), p1_=__expf(s0_[1]-m), p2_=__expf(s0_[2]-m), p3_=__expf(s0_[3]-m); \
  float p4_=__expf(s1_[0]-m), p5_=__expf(s1_[1]-m), p6_=__expf(s1_[2]-m), p7_=__expf(s1_[3]-m); \
  float p8_=__expf(s2_[0]-m), p9_=__expf(s2_[1]-m), pA_=__expf(s2_[2]-m), pB_=__expf(s2_[3]-m); \
  float pC_=__expf(s3_[0]-m), pD_=__expf(s3_[1]-m), pE_=__expf(s3_[2]-m), pF_=__expf(s3_[3]-m); \
  l += ((((p0_+p1_)+(p2_+p3_)) + ((p4_+p5_)+(p6_+p7_))) +           \
        (((p8_+p9_)+(pA_+pB_)) + ((pC_+pD_)+(pE_+pF_))));           \
  uint4 uA_ = { pk2(p0_,p1_), pk2(p2_,p3_), pk2(p4_,p5_), pk2(p6_,p7_) }; \
  uint4 uB_ = { pk2(p8_,p9_), pk2(pA_,pB_), pk2(pC_,pD_), pk2(pE_,pF_) }; \
  short8v pbA_ = __builtin_bit_cast(short8v, uA_);                  \
  short8v pbB_ = __builtin_bit_cast(short8v, uB_);                  \
  short8v va0_ = {W0.x,W0.y,W0.z,W0.w, W1.x,W1.y,W1.z,W1.w};        \
  short8v va1_ = {W2.x,W2.y,W2.z,W2.w, W3.x,W3.y,W3.z,W3.w};        \
  short8v vb0_ = {X0.x,X0.y,X0.z,X0.w, X1.x,X1.y,X1.z,X1.w};        \
  short8v vb1_ = {X2.x,X2.y,X2.z,X2.w, X3.x,X3.y,X3.z,X3.w};        \
  acc0 = MFMA16(va0_, pbA_, acc0);                                  \
  acc0 = MFMA16(va1_, pbB_, acc0);                                  \
  acc1 = MFMA16(vb0_, pbA_, acc1);                                  \
  acc1 = MFMA16(vb1_, pbB_, acc1);                                  \
} while (0)

__global__ __launch_bounds__(256) void attn_mfma_split(
    const unsigned short* __restrict__ qkvb, const unsigned short* __restrict__ VT,
    float* __restrict__ po, float* __restrict__ ml, int kspan) {
  int tid = threadIdx.x;
  int w = tid >> 6, lane = tid & 63;
  int lo = lane & 15, g = lane >> 4;
  int h = blockIdx.y;
  int s = blockIdx.z;
  int qb = blockIdx.x * 64 + w * 16;
  int k_lo = s * kspan, k_hi = k_lo + kspan;

  // Q B-frag: col=q=qb+lo, contraction d = 8g..8g+7
  short8v qf = *(const short8v*)(qkvb + (size_t)(qb + lo) * 768 + h * 32 + 8 * g);

  f32x4 acc0 = {0.f, 0.f, 0.f, 0.f};   // O^T[d=4g+r][q=lo]
  f32x4 acc1 = {0.f, 0.f, 0.f, 0.f};   // O^T[d=16+4g+r][q=lo]
  float m = -1e30f, l = 0.f;

  const unsigned short* Kp  = qkvb + 256 + h * 32 + 8 * g;              // + k*768
  const unsigned short* Vp0 = VT + ((size_t)(h * 32 + lo)) * 4096 + 4 * g;      // d=lo
  const unsigned short* Vp1 = VT + ((size_t)(h * 32 + 16 + lo)) * 4096 + 4 * g; // d=lo+16
  const f32x4 zf = {0.f, 0.f, 0.f, 0.f};

  short8v Ka0, Ka1, Ka2, Ka3, Kb0, Kb1, Kb2, Kb3;
  short4 Wa0, Wa1, Wa2, Wa3, Xa0, Xa1, Xa2, Xa3;
  short4 Wb0, Wb1, Wb2, Wb3, Xb0, Xb1, Xb2, Xb3;

  LK(k_lo, Ka0, Ka1, Ka2, Ka3);
  LV(k_lo, Wa0, Wa1, Wa2, Wa3, Xa0, Xa1, Xa2, Xa3);

  for (int kb = k_lo; kb < k_hi; kb += 128) {
    LK(kb + 64, Kb0, Kb1, Kb2, Kb3);
    LV(kb + 64, Wb0, Wb1, Wb2, Wb3, Xb0, Xb1, Xb2, Xb3);
    STEP(Ka0, Ka1, Ka2, Ka3, Wa0, Wa1, Wa2, Wa3, Xa0, Xa1, Xa2, Xa3);
    int kn = (kb + 128 < k_hi) ? (kb + 128) : k_lo;
    LK(kn, Ka0, Ka1, Ka2, Ka3);
    LV(kn, Wa0, Wa1, Wa2, Wa3, Xa0, Xa1, Xa2, Xa3);
    STEP(Kb0, Kb1, Kb2, Kb3, Wb0, Wb1, Wb2, Wb3, Xb0, Xb1, Xb2, Xb3);
  }

  // finalize l across the 4 g-lanes (m already synced)
  l += __shfl_xor(l, 16, 64);
  l += __shfl_xor(l, 32, 64);

  int q = qb + lo;
  float* pr = po + ((size_t)s * NN + q) * DIM + h * 32 + 4 * g;
  *(f32x4*)pr = acc0;
  *(f32x4*)(pr + 16) = acc1;
  if (g == 0) {
    float2* mlp = (float2*)(ml + (((size_t)s * NN + q) * NHEAD + h) * 2);
    *mlp = float2{m, l};
  }
}

// combine k-splits: attb[q][c] = sum_s e^{m_s-M} po_s / sum_s e^{m_s-M} l_s
__global__ __launch_bounds__(256) void attn_merge(const float* __restrict__ po,
                                                  const float* __restrict__ ml,
                                                  unsigned short* __restrict__ attb, int S) {
  int q = blockIdx.x;
  int c = threadIdx.x;
  int h = c >> 5;
  float M = -1e30f;
  for (int s = 0; s < S; s++)
    M = fmaxf(M, ml[(((size_t)s * NN + q) * NHEAD + h) * 2]);
  float L = 0.f, O = 0.f;
  for (int s = 0; s < S; s++) {
    const float* mlp = ml + (((size_t)s * NN + q) * NHEAD + h) * 2;
    float e = __expf(mlp[0] - M);
    L += e * mlp[1];
    O += e * po[((size_t)s * NN + q) * DIM + c];
  }
  attb[(size_t)q * DIM + c] = f2bf(O / L);
}

// ---------------- weight conversion ----------------
#define WO0 0
#define WO1 131072
#define WO2 262144
#define WO3 655360
#define WO4 786432
#define WO5 1048576
#define WO6 1310720
#define WTOT 1343488
__global__ __launch_bounds__(256) void wconv(const float* __restrict__ s0, const float* __restrict__ s1,
                                             const float* __restrict__ s2, const float* __restrict__ s3,
                                             const float* __restrict__ s4, const float* __restrict__ s5,
                                             const float* __restrict__ s6, unsigned short* __restrict__ dst) {
  int i4 = (blockIdx.x * 256 + threadIdx.x) * 4;
  if (i4 >= WTOT) return;
  const float* src; int loc;
  if      (i4 < WO1) { src = s0; loc = i4 - WO0; }
  else if (i4 < WO2) { src = s1; loc = i4 - WO1; }
  else if (i4 < WO3) { src = s2; loc = i4 - WO2; }
  else if (i4 < WO4) { src = s3; loc = i4 - WO3; }
  else if (i4 < WO5) { src = s4; loc = i4 - WO4; }
  else if (i4 < WO6) { src = s5; loc = i4 - WO5; }
  else               { src = s6; loc = i4 - WO6; }
  float4 v = *(const float4*)(src + loc);
  ushort4 o;
  o.x = f2bf(v.x); o.y = f2bf(v.y); o.z = f2bf(v.z); o.w = f2bf(v.w);
  *(ushort4*)(dst + i4) = o;
}

__global__ __launch_bounds__(256) void pad72_96(const float* __restrict__ src,
                                                unsigned short* __restrict__ dst, int total) {
  int idx = blockIdx.x * 256 + threadIdx.x;
  if (idx >= total) return;
  int row = idx / 96, col = idx - row * 96;
  dst[idx] = (col < 72) ? f2bf(src[row * 72 + col]) : (unsigned short)0;
}

// ---------------- tiny head ----------------
__global__ void head2_kernel(const float* __restrict__ e, const float* __restrict__ w,
                             const float* __restrict__ b, float* __restrict__ out) {
  int idx = blockIdx.x * 256 + threadIdx.x;
  if (idx >= NN * 5) return;
  int rowi = idx / 5, col = idx % 5;
  float s = b[col];
  const float* ep = e + (size_t)rowi * 128;
  const float* wp = w + (size_t)col * 128;
  #pragma unroll 16
  for (int k = 0; k < 128; k++) s += ep[k] * wp[k];
  out[idx] = s;
}

extern "C" void kernel_launch(void* const* d_in, const int* in_sizes, int n_in,
                              void* d_out, int out_size, void* d_ws, size_t ws_size,
                              hipStream_t stream) {
  const float* x_in   = (const float*)d_in[0];
  const int*   ei     = (const int*)  d_in[1];
  const float* in_w   = (const float*)d_in[2];
  const float* in_b   = (const float*)d_in[3];
  const float* head_w1= (const float*)d_in[4];
  const float* head_b1= (const float*)d_in[5];
  const float* head_w2= (const float*)d_in[6];
  const float* head_b2= (const float*)d_in[7];
  const float* mlp_w1 = (const float*)d_in[8];
  const float* mlp_b1 = (const float*)d_in[9];
  const float* mlp_w2 = (const float*)d_in[10];
  const float* mlp_b2 = (const float*)d_in[11];
  const float* gin_eps= (const float*)d_in[12];
  const float* ln1_g  = (const float*)d_in[13];
  const float* ln1_b  = (const float*)d_in[14];
  const float* attn_in_w = (const float*)d_in[15];
  const float* attn_in_b = (const float*)d_in[16];
  const float* attn_out_w= (const float*)d_in[17];
  const float* attn_out_b= (const float*)d_in[18];
  const float* ln2_g  = (const float*)d_in[19];
  const float* ln2_b  = (const float*)d_in[20];
  const float* ffn_w1 = (const float*)d_in[21];
  const float* ffn_b1 = (const float*)d_in[22];
  const float* ffn_w2 = (const float*)d_in[23];
  const float* ffn_b2 = (const float*)d_in[24];
  const float* ln3_g  = (const float*)d_in[25];
  const float* ln3_b  = (const float*)d_in[26];

  float* ws = (float*)d_ws;
  float* x    = ws;                              // [NN,256] f32
  float* t2   = x  + (size_t)NN * DIM;           // [NN,256] f32
  float* he   = t2 + (size_t)NN * DIM;           // [NN,128] f32
  unsigned short* xb   = (unsigned short*)(he + (size_t)NN * 128);
  unsigned short* tbb  = xb   + (size_t)NN * DIM;       // [NN,768] bf16
  unsigned short* aggb = tbb  + (size_t)NN * 768;       // [NN,256] bf16
  unsigned short* attb = aggb + (size_t)NN * DIM;       // [NN,256] bf16
  unsigned short* VT   = attb + (size_t)NN * DIM;       // [256][NN] bf16
  unsigned short* xinb = VT   + (size_t)NN * DIM;       // [NN][96] bf16
  unsigned short* inwb = xinb + (size_t)NN * 96;        // [256][96] bf16
  unsigned short* warena = inwb + 256 * 96;             // WTOT bf16
  int* counts = (int*)(warena + WTOT);
  int* offs   = counts + NN;       // NN+1
  int* cursor = offs + NN + 1;
  int* esrc   = cursor + NN;       // NE
  float* po   = (float*)(esrc + NE);   // [S][NN][DIM] f32
  size_t used_f = (size_t)(po - ws);
  int S = 1;
  for (int cand = 4; cand >= 2; cand >>= 1) {
    size_t need = (used_f + (size_t)cand * NN * DIM + (size_t)cand * NN * NHEAD * 2) * 4;
    if (ws_size >= need) { S = cand; break; }
  }
  float* ml = po + (size_t)S * NN * DIM;
  int kspan = NN / S;

  const unsigned short* w_mlp1 = warena + WO0;
  const unsigned short* w_mlp2 = warena + WO1;
  const unsigned short* w_qkv  = warena + WO2;
  const unsigned short* w_aout = warena + WO3;
  const unsigned short* w_ffn1 = warena + WO4;
  const unsigned short* w_ffn2 = warena + WO5;
  const unsigned short* w_h1   = warena + WO6;

  // CSR build
  zero_counts<<<16, 256, 0, stream>>>(counts);
  count_edges<<<NE / 256, 256, 0, stream>>>(ei, counts);
  scan_offsets<<<1, 1024, 0, stream>>>(counts, offs, cursor);
  scatter_edges<<<NE / 256, 256, 0, stream>>>(ei, cursor, esrc);

  // weight + input conversions
  wconv<<<1312, 256, 0, stream>>>(mlp_w1, mlp_w2, attn_in_w, attn_out_w, ffn_w1, ffn_w2,
                                  head_w1, warena);
  pad72_96<<<(NN * 96 + 255) / 256, 256, 0, stream>>>(x_in, xinb, NN * 96);
  pad72_96<<<(256 * 96 + 255) / 256, 256, 0, stream>>>(in_w, inwb, 256 * 96);

  // input projection
  gemm_mfma<1,1,1,0><<<dim3(DIM/64, NN/64), 256, 0, stream>>>(xinb, inwb, in_b, x, xb,
                                                              NN, DIM, 96);

  for (int l = 0; l < 2; l++) {
    // GIN
    gin_agg<<<NN, 256, 0, stream>>>(offs, esrc, x, gin_eps, l, aggb);
    gemm_mfma<1,0,1,0><<<dim3(4, 64), 256, 0, stream>>>(aggb, w_mlp1 + (size_t)l*65536,
                                                        mlp_b1 + l*DIM, nullptr, tbb,
                                                        NN, DIM, DIM);
    gemm_mfma<0,1,0,0><<<dim3(4, 64), 256, 0, stream>>>(tbb, w_mlp2 + (size_t)l*65536,
                                                        mlp_b2 + l*DIM, t2, nullptr,
                                                        NN, DIM, DIM);
    ln_act_add<1><<<NN, 256, 0, stream>>>(t2, ln1_g + l*DIM, ln1_b + l*DIM, x, xb);

    // attention
    gemm_mfma<0,0,1,1><<<dim3(12, 64), 256, 0, stream>>>(xb, w_qkv + (size_t)l*196608,
                                                         attn_in_b + l*768, nullptr, tbb,
                                                         NN, 768, DIM);
    vt_transpose<<<dim3(32, 8), 256, 0, stream>>>(tbb, VT);
    attn_mfma_split<<<dim3(64, NHEAD, S), 256, 0, stream>>>(tbb, VT, po, ml, kspan);
    attn_merge<<<NN, 256, 0, stream>>>(po, ml, attb, S);
    gemm_mfma<0,1,0,0><<<dim3(4, 64), 256, 0, stream>>>(attb, w_aout + (size_t)l*65536,
                                                        attn_out_b + l*DIM, t2, nullptr,
                                                        NN, DIM, DIM);
    ln_act_add<0><<<NN, 256, 0, stream>>>(t2, ln2_g + l*DIM, ln2_b + l*DIM, x, xb);

    // FFN
    gemm_mfma<2,0,1,0><<<dim3(8, 64), 256, 0, stream>>>(xb, w_ffn1 + (size_t)l*131072,
                                                        ffn_b1 + l*512, nullptr, tbb,
                                                        NN, 512, DIM);
    gemm_mfma<0,1,0,0><<<dim3(4, 64), 256, 0, stream>>>(tbb, w_ffn2 + (size_t)l*131072,
                                                        ffn_b2 + l*DIM, t2, nullptr,
                                                        NN, DIM, 512);
    ln_act_add<0><<<NN, 256, 0, stream>>>(t2, ln3_g + l*DIM, ln3_b + l*DIM, x, xb);
  }

  // head
  gemm_mfma<1,1,0,0><<<dim3(2, 64), 256, 0, stream>>>(xb, w_h1, head_b1, he, nullptr,
                                                      NN, 128, DIM);
  head2_kernel<<<(NN * 5 + 255) / 256, 256, 0, stream>>>(he, head_w2, head_b2, (float*)d_out);
}

// Round 8
// 363.678 us; speedup vs baseline: 1.9786x; 1.7050x over previous
//
#include <hip/hip_runtime.h>
#include <math.h>

#define NN 4096
#define NE 131072
#define DIM 256
#define NHEAD 8
#define HD 32

typedef __attribute__((ext_vector_type(8))) short short8v;
typedef __attribute__((ext_vector_type(4))) float f32x4;
#define MFMA16(a, b, c) __builtin_amdgcn_mfma_f32_16x16x32_bf16(a, b, c, 0, 0, 0)

__device__ __forceinline__ float elu_f(float v){ return v > 0.f ? v : expm1f(v); }
__device__ __forceinline__ float gelu_f(float v){
  const float c = 0.7978845608028654f;
  float t = tanhf(c * (v + 0.044715f * v * v * v));
  return 0.5f * v * (1.f + t);
}
__device__ __forceinline__ unsigned short f2bf(float f) {
  unsigned int u = __builtin_bit_cast(unsigned int, f);
  u += 0x7FFFu + ((u >> 16) & 1u);
  return (unsigned short)(u >> 16);
}
__device__ __forceinline__ unsigned int pk2(float a, float b) {
  return (unsigned int)f2bf(a) | ((unsigned int)f2bf(b) << 16);
}

// ---------------- CSR build ----------------
__global__ void zero_counts(int* __restrict__ counts) {
  int i = blockIdx.x * 256 + threadIdx.x;
  if (i < NN) counts[i] = 0;
}

__global__ void count_edges(const int* __restrict__ ei, int* __restrict__ counts) {
  int e = blockIdx.x * 256 + threadIdx.x;
  if (e < NE) atomicAdd(&counts[ei[NE + e]], 1);
}

__global__ __launch_bounds__(1024) void scan_offsets(const int* __restrict__ counts,
                                                     int* __restrict__ offs,
                                                     int* __restrict__ cursor) {
  __shared__ int tmp[1024];
  int t = threadIdx.x;
  int base = t * 4;
  int c0 = counts[base], c1 = counts[base+1], c2 = counts[base+2], c3 = counts[base+3];
  int tsum = c0 + c1 + c2 + c3;
  tmp[t] = tsum;
  __syncthreads();
  for (int d = 1; d < 1024; d <<= 1) {
    int v = (t >= d) ? tmp[t - d] : 0;
    __syncthreads();
    tmp[t] += v;
    __syncthreads();
  }
  int excl = tmp[t] - tsum;
  offs[base]   = excl;           cursor[base]   = excl;
  offs[base+1] = excl + c0;      cursor[base+1] = excl + c0;
  offs[base+2] = excl + c0 + c1; cursor[base+2] = excl + c0 + c1;
  offs[base+3] = excl + c0 + c1 + c2; cursor[base+3] = excl + c0 + c1 + c2;
  if (t == 1023) offs[NN] = tmp[1023];
}

__global__ void scatter_edges(const int* __restrict__ ei, int* __restrict__ cursor,
                              int* __restrict__ esrc) {
  int e = blockIdx.x * 256 + threadIdx.x;
  if (e < NE) {
    int d = ei[NE + e];
    int pos = atomicAdd(&cursor[d], 1);
    esrc[pos] = ei[e];
  }
}

// block per node: aggb[n][c] = bf16( (1+eps)*x[n][c] + sum_{e} x[src_e][c] )
__global__ __launch_bounds__(256) void gin_agg(const int* __restrict__ offs,
                                               const int* __restrict__ esrc,
                                               const float* __restrict__ x,
                                               const float* __restrict__ eps_p, int l,
                                               unsigned short* __restrict__ aggb) {
  int n = blockIdx.x, c = threadIdx.x;
  int e0 = offs[n], e1 = offs[n + 1];
  float acc = 0.f;
  for (int e = e0; e < e1; e++) acc += x[(size_t)esrc[e] * DIM + c];
  float eps = eps_p[l];
  aggb[(size_t)n * DIM + c] = f2bf((1.f + eps) * x[(size_t)n * DIM + c] + acc);
}

// ---------------- bf16 MFMA GEMM: C = act(A @ W^T + bias) ----------------
template<int ACT, int WF32, int WBF16, int QSCALE>
__global__ __launch_bounds__(256) void gemm_mfma(
    const unsigned short* __restrict__ A, const unsigned short* __restrict__ W,
    const float* __restrict__ bias, float* __restrict__ Cf,
    unsigned short* __restrict__ Cb, int M, int N, int K)
{
  __shared__ __align__(16) unsigned short As[64][40];
  __shared__ __align__(16) unsigned short Ws[64][40];
  int t = threadIdx.x;
  int w = t >> 6, lane = t & 63, lo = lane & 15, g = lane >> 4;
  int wr = w >> 1, wc = w & 1;
  int bn = blockIdx.x * 64, bm = blockIdx.y * 64;
  int srow = t >> 2, skk = (t & 3) << 3;
  const unsigned short* ap = A + (size_t)(bm + srow) * K + skk;
  const unsigned short* wp = W + (size_t)(bn + srow) * K + skk;

  f32x4 acc[2][2] = {{{0.f,0.f,0.f,0.f},{0.f,0.f,0.f,0.f}},
                     {{0.f,0.f,0.f,0.f},{0.f,0.f,0.f,0.f}}};

  for (int k0 = 0; k0 < K; k0 += 32) {
    *(short8v*)&As[srow][skk] = *(const short8v*)(ap + k0);
    *(short8v*)&Ws[srow][skk] = *(const short8v*)(wp + k0);
    __syncthreads();
    short8v a0 = *(const short8v*)&As[wr * 32 + lo][8 * g];
    short8v a1 = *(const short8v*)&As[wr * 32 + 16 + lo][8 * g];
    short8v b0 = *(const short8v*)&Ws[wc * 32 + lo][8 * g];
    short8v b1 = *(const short8v*)&Ws[wc * 32 + 16 + lo][8 * g];
    acc[0][0] = MFMA16(a0, b0, acc[0][0]);
    acc[0][1] = MFMA16(a0, b1, acc[0][1]);
    acc[1][0] = MFMA16(a1, b0, acc[1][0]);
    acc[1][1] = MFMA16(a1, b1, acc[1][1]);
    __syncthreads();
  }

  #pragma unroll
  for (int mi = 0; mi < 2; mi++) {
    #pragma unroll
    for (int ni = 0; ni < 2; ni++) {
      #pragma unroll
      for (int r = 0; r < 4; r++) {
        int row = bm + wr * 32 + mi * 16 + 4 * g + r;
        int col = bn + wc * 32 + ni * 16 + lo;
        float v = acc[mi][ni][r] + bias[col];
        if (ACT == 1) v = elu_f(v);
        if (ACT == 2) v = gelu_f(v);
        if (QSCALE) { if (col < 256) v *= 0.17677669529663687f; }
        if (WF32) Cf[(size_t)row * N + col] = v;
        if (WBF16) Cb[(size_t)row * N + col] = f2bf(v);
      }
    }
  }
}

// ---------------- LayerNorm(+act) + residual add; also emits bf16 copy ----------------
template<int ACT>
__global__ __launch_bounds__(256) void ln_act_add(const float* __restrict__ in,
                                                  const float* __restrict__ g,
                                                  const float* __restrict__ b,
                                                  float* __restrict__ x,
                                                  unsigned short* __restrict__ xb) {
  int rowb = blockIdx.x;
  int c = threadIdx.x;
  float v = in[(size_t)rowb * DIM + c];
  float s = v, s2 = v * v;
  #pragma unroll
  for (int off = 32; off >= 1; off >>= 1) {
    s  += __shfl_xor(s,  off, 64);
    s2 += __shfl_xor(s2, off, 64);
  }
  __shared__ float ws1[4], ws2[4];
  int w = threadIdx.x >> 6, lane = threadIdx.x & 63;
  if (lane == 0) { ws1[w] = s; ws2[w] = s2; }
  __syncthreads();
  s  = ws1[0] + ws1[1] + ws1[2] + ws1[3];
  s2 = ws2[0] + ws2[1] + ws2[2] + ws2[3];
  float mean = s * (1.f / DIM);
  float var = s2 * (1.f / DIM) - mean * mean;
  float r = rsqrtf(var + 1e-5f);
  float o = (v - mean) * r * g[c] + b[c];
  if (ACT == 1) o = elu_f(o);
  float nx = x[(size_t)rowb * DIM + c] + o;
  x[(size_t)rowb * DIM + c] = nx;
  xb[(size_t)rowb * DIM + c] = f2bf(nx);
}

// ---------------- V transpose ----------------
__global__ __launch_bounds__(256) void vt_transpose(const unsigned short* __restrict__ tbb,
                                                    unsigned short* __restrict__ VT) {
  __shared__ unsigned short lds[128][33];
  int h = blockIdx.y;
  int nb = blockIdx.x * 128;
  int tid = threadIdx.x;
  int r8 = tid >> 5, d = tid & 31;
  #pragma unroll
  for (int i = 0; i < 16; i++) {
    int n = i * 8 + r8;
    lds[n][d] = tbb[(size_t)(nb + n) * 768 + 512 + h * 32 + d];
  }
  __syncthreads();
  int dd = tid >> 7, j = tid & 127;
  #pragma unroll
  for (int i = 0; i < 16; i++) {
    int d2 = i * 2 + dd;
    VT[((size_t)h * 32 + d2) * 4096 + nb + j] = lds[j][d2];
  }
}

// ---------------- MFMA flash attention v5: LDS-shared K/V + in-register softmax ----------
// Block: 4 waves x 16 q-rows = 64 q, one head, k-span blockIdx.z.
// Per 64-k tile: K/V staged cooperatively to double-buffered LDS (1 barrier/tile);
// compute uses the verified swapped-QK^T + permuted-PV in-register softmax.
__global__ __launch_bounds__(256) void attn_mfma_split(
    const unsigned short* __restrict__ qkvb, const unsigned short* __restrict__ VT,
    float* __restrict__ po, float* __restrict__ ml, int kspan) {
  __shared__ __align__(16) unsigned short Ks[2][64][40];   // 80B rows: 2-way banks (free)
  __shared__ __align__(16) unsigned short Vs[2][32][72];   // 144B rows: 2-way banks (free)
  int tid = threadIdx.x;
  int w = tid >> 6, lane = tid & 63;
  int lo = lane & 15, g = lane >> 4;
  int h = blockIdx.y;
  int s = blockIdx.z;
  int qb = blockIdx.x * 64 + w * 16;
  int k_lo = s * kspan, k_hi = k_lo + kspan;

  // staging roles
  int krow = tid >> 2, kq = (tid & 3) * 8;    // K: 64 rows x 4x16B
  int vrow = tid >> 3, vo = (tid & 7) * 8;    // V: 32 rows x 8x16B
  const unsigned short* Kg = qkvb + 256 + h * 32;                     // + k*768 + kq
  const unsigned short* Vg = VT + ((size_t)(h * 32 + vrow)) * 4096;   // + kb + vo

  // Q B-frag: col=q=qb+lo, contraction d = 8g..8g+7
  short8v qf = *(const short8v*)(qkvb + (size_t)(qb + lo) * 768 + h * 32 + 8 * g);

  f32x4 acc0 = {0.f, 0.f, 0.f, 0.f};   // O^T[d=4g+r][q=lo]
  f32x4 acc1 = {0.f, 0.f, 0.f, 0.f};   // O^T[d=16+4g+r][q=lo]
  float m = -1e30f, l = 0.f;
  const f32x4 zf = {0.f, 0.f, 0.f, 0.f};

  // stage first tile into buf 0
  {
    short8v rk0 = *(const short8v*)(Kg + (size_t)(k_lo + krow) * 768 + kq);
    short8v rv0 = *(const short8v*)(Vg + k_lo + vo);
    *(short8v*)&Ks[0][krow][kq] = rk0;
    *(short8v*)&Vs[0][vrow][vo] = rv0;
  }
  __syncthreads();

  int buf = 0;
  for (int kb = k_lo; kb < k_hi; kb += 64) {
    // issue next tile's global loads early (latency hides under compute)
    short8v rk, rv;
    bool more = (kb + 64 < k_hi);
    if (more) {
      rk = *(const short8v*)(Kg + (size_t)(kb + 64 + krow) * 768 + kq);
      rv = *(const short8v*)(Vg + kb + 64 + vo);
    }

    // ---- compute tile from LDS buf ----
    short8v kA0 = *(const short8v*)&Ks[buf][lo][8 * g];
    short8v kA1 = *(const short8v*)&Ks[buf][16 + lo][8 * g];
    short8v kA2 = *(const short8v*)&Ks[buf][32 + lo][8 * g];
    short8v kA3 = *(const short8v*)&Ks[buf][48 + lo][8 * g];
    f32x4 s0_ = MFMA16(kA0, qf, zf);
    f32x4 s1_ = MFMA16(kA1, qf, zf);
    f32x4 s2_ = MFMA16(kA2, qf, zf);
    f32x4 s3_ = MFMA16(kA3, qf, zf);

    float ta_ = fmaxf(fmaxf(fmaxf(s0_[0],s0_[1]), fmaxf(s0_[2],s0_[3])),
                      fmaxf(fmaxf(s1_[0],s1_[1]), fmaxf(s1_[2],s1_[3])));
    float tb_ = fmaxf(fmaxf(fmaxf(s2_[0],s2_[1]), fmaxf(s2_[2],s2_[3])),
                      fmaxf(fmaxf(s3_[0],s3_[1]), fmaxf(s3_[2],s3_[3])));
    float t_ = fmaxf(ta_, tb_);
    t_ = fmaxf(t_, __shfl_xor(t_, 16, 64));
    t_ = fmaxf(t_, __shfl_xor(t_, 32, 64));
    if (!__all(t_ <= m)) {
      float nm_ = fmaxf(m, t_);
      float f_ = __expf(m - nm_);
      m = nm_; l *= f_;
      acc0[0]*=f_; acc0[1]*=f_; acc0[2]*=f_; acc0[3]*=f_;
      acc1[0]*=f_; acc1[1]*=f_; acc1[2]*=f_; acc1[3]*=f_;
    }
    float p0_=__expf(s0_[0]-m), p1_=__expf(s0_[1]-m), p2_=__expf(s0_[2]-m), p3_=__expf(s0_[3]-m);
    float p4_=__expf(s1_[0]-m), p5_=__expf(s1_[1]-m), p6_=__expf(s1_[2]-m), p7_=__expf(s1_[3]-m);
    float p8_=__expf(s2_[0]-m), p9_=__expf(s2_[1]-m), pA_=__expf(s2_[2]-m), pB_=__expf(s2_[3]-m);
    float pC_=__expf(s3_[0]-m), pD_=__expf(s3_[1]-m), pE_=__expf(s3_[2]-m), pF_=__expf(s3_[3]-m);
    l += ((((p0_+p1_)+(p2_+p3_)) + ((p4_+p5_)+(p6_+p7_))) +
          (((p8_+p9_)+(pA_+pB_)) + ((pC_+pD_)+(pE_+pF_))));

    uint4 uA_ = { pk2(p0_,p1_), pk2(p2_,p3_), pk2(p4_,p5_), pk2(p6_,p7_) };
    uint4 uB_ = { pk2(p8_,p9_), pk2(pA_,pB_), pk2(pC_,pD_), pk2(pE_,pF_) };
    short8v pbA_ = __builtin_bit_cast(short8v, uA_);
    short8v pbB_ = __builtin_bit_cast(short8v, uB_);

    // V^T A-frags, permuted slots: k = {4g..4g+3, 16+4g..} (pbA_), +32 (pbB_)
    short4 Wa0 = *(const short4*)&Vs[buf][lo][4 * g];
    short4 Wa1 = *(const short4*)&Vs[buf][lo][16 + 4 * g];
    short4 Wa2 = *(const short4*)&Vs[buf][lo][32 + 4 * g];
    short4 Wa3 = *(const short4*)&Vs[buf][lo][48 + 4 * g];
    short4 Xa0 = *(const short4*)&Vs[buf][16 + lo][4 * g];
    short4 Xa1 = *(const short4*)&Vs[buf][16 + lo][16 + 4 * g];
    short4 Xa2 = *(const short4*)&Vs[buf][16 + lo][32 + 4 * g];
    short4 Xa3 = *(const short4*)&Vs[buf][16 + lo][48 + 4 * g];
    short8v va0_ = {Wa0.x,Wa0.y,Wa0.z,Wa0.w, Wa1.x,Wa1.y,Wa1.z,Wa1.w};
    short8v va1_ = {Wa2.x,Wa2.y,Wa2.z,Wa2.w, Wa3.x,Wa3.y,Wa3.z,Wa3.w};
    short8v vb0_ = {Xa0.x,Xa0.y,Xa0.z,Xa0.w, Xa1.x,Xa1.y,Xa1.z,Xa1.w};
    short8v vb1_ = {Xa2.x,Xa2.y,Xa2.z,Xa2.w, Xa3.x,Xa3.y,Xa3.z,Xa3.w};
    acc0 = MFMA16(va0_, pbA_, acc0);
    acc0 = MFMA16(va1_, pbB_, acc0);
    acc1 = MFMA16(vb0_, pbA_, acc1);
    acc1 = MFMA16(vb1_, pbB_, acc1);

    // ---- write next tile into the other buffer; 1 barrier/tile ----
    if (more) {
      *(short8v*)&Ks[buf ^ 1][krow][kq] = rk;
      *(short8v*)&Vs[buf ^ 1][vrow][vo] = rv;
    }
    __syncthreads();
    buf ^= 1;
  }

  // finalize l across the 4 g-lanes (m already synced)
  l += __shfl_xor(l, 16, 64);
  l += __shfl_xor(l, 32, 64);

  int q = qb + lo;
  float* pr = po + ((size_t)s * NN + q) * DIM + h * 32 + 4 * g;
  *(f32x4*)pr = acc0;
  *(f32x4*)(pr + 16) = acc1;
  if (g == 0) {
    float2* mlp = (float2*)(ml + (((size_t)s * NN + q) * NHEAD + h) * 2);
    *mlp = float2{m, l};
  }
}

// combine k-splits: attb[q][c] = sum_s e^{m_s-M} po_s / sum_s e^{m_s-M} l_s
__global__ __launch_bounds__(256) void attn_merge(const float* __restrict__ po,
                                                  const float* __restrict__ ml,
                                                  unsigned short* __restrict__ attb, int S) {
  int q = blockIdx.x;
  int c = threadIdx.x;
  int h = c >> 5;
  float M = -1e30f;
  for (int s = 0; s < S; s++)
    M = fmaxf(M, ml[(((size_t)s * NN + q) * NHEAD + h) * 2]);
  float L = 0.f, O = 0.f;
  for (int s = 0; s < S; s++) {
    const float* mlp = ml + (((size_t)s * NN + q) * NHEAD + h) * 2;
    float e = __expf(mlp[0] - M);
    L += e * mlp[1];
    O += e * po[((size_t)s * NN + q) * DIM + c];
  }
  attb[(size_t)q * DIM + c] = f2bf(O / L);
}

// ---------------- weight conversion ----------------
#define WO0 0
#define WO1 131072
#define WO2 262144
#define WO3 655360
#define WO4 786432
#define WO5 1048576
#define WO6 1310720
#define WTOT 1343488
__global__ __launch_bounds__(256) void wconv(const float* __restrict__ s0, const float* __restrict__ s1,
                                             const float* __restrict__ s2, const float* __restrict__ s3,
                                             const float* __restrict__ s4, const float* __restrict__ s5,
                                             const float* __restrict__ s6, unsigned short* __restrict__ dst) {
  int i4 = (blockIdx.x * 256 + threadIdx.x) * 4;
  if (i4 >= WTOT) return;
  const float* src; int loc;
  if      (i4 < WO1) { src = s0; loc = i4 - WO0; }
  else if (i4 < WO2) { src = s1; loc = i4 - WO1; }
  else if (i4 < WO3) { src = s2; loc = i4 - WO2; }
  else if (i4 < WO4) { src = s3; loc = i4 - WO3; }
  else if (i4 < WO5) { src = s4; loc = i4 - WO4; }
  else if (i4 < WO6) { src = s5; loc = i4 - WO5; }
  else               { src = s6; loc = i4 - WO6; }
  float4 v = *(const float4*)(src + loc);
  ushort4 o;
  o.x = f2bf(v.x); o.y = f2bf(v.y); o.z = f2bf(v.z); o.w = f2bf(v.w);
  *(ushort4*)(dst + i4) = o;
}

__global__ __launch_bounds__(256) void pad72_96(const float* __restrict__ src,
                                                unsigned short* __restrict__ dst, int total) {
  int idx = blockIdx.x * 256 + threadIdx.x;
  if (idx >= total) return;
  int row = idx / 96, col = idx - row * 96;
  dst[idx] = (col < 72) ? f2bf(src[row * 72 + col]) : (unsigned short)0;
}

// ---------------- tiny head ----------------
__global__ void head2_kernel(const float* __restrict__ e, const float* __restrict__ w,
                             const float* __restrict__ b, float* __restrict__ out) {
  int idx = blockIdx.x * 256 + threadIdx.x;
  if (idx >= NN * 5) return;
  int rowi = idx / 5, col = idx % 5;
  float s = b[col];
  const float* ep = e + (size_t)rowi * 128;
  const float* wp = w + (size_t)col * 128;
  #pragma unroll 16
  for (int k = 0; k < 128; k++) s += ep[k] * wp[k];
  out[idx] = s;
}

extern "C" void kernel_launch(void* const* d_in, const int* in_sizes, int n_in,
                              void* d_out, int out_size, void* d_ws, size_t ws_size,
                              hipStream_t stream) {
  const float* x_in   = (const float*)d_in[0];
  const int*   ei     = (const int*)  d_in[1];
  const float* in_w   = (const float*)d_in[2];
  const float* in_b   = (const float*)d_in[3];
  const float* head_w1= (const float*)d_in[4];
  const float* head_b1= (const float*)d_in[5];
  const float* head_w2= (const float*)d_in[6];
  const float* head_b2= (const float*)d_in[7];
  const float* mlp_w1 = (const float*)d_in[8];
  const float* mlp_b1 = (const float*)d_in[9];
  const float* mlp_w2 = (const float*)d_in[10];
  const float* mlp_b2 = (const float*)d_in[11];
  const float* gin_eps= (const float*)d_in[12];
  const float* ln1_g  = (const float*)d_in[13];
  const float* ln1_b  = (const float*)d_in[14];
  const float* attn_in_w = (const float*)d_in[15];
  const float* attn_in_b = (const float*)d_in[16];
  const float* attn_out_w= (const float*)d_in[17];
  const float* attn_out_b= (const float*)d_in[18];
  const float* ln2_g  = (const float*)d_in[19];
  const float* ln2_b  = (const float*)d_in[20];
  const float* ffn_w1 = (const float*)d_in[21];
  const float* ffn_b1 = (const float*)d_in[22];
  const float* ffn_w2 = (const float*)d_in[23];
  const float* ffn_b2 = (const float*)d_in[24];
  const float* ln3_g  = (const float*)d_in[25];
  const float* ln3_b  = (const float*)d_in[26];

  float* ws = (float*)d_ws;
  float* x    = ws;                              // [NN,256] f32
  float* t2   = x  + (size_t)NN * DIM;           // [NN,256] f32
  float* he   = t2 + (size_t)NN * DIM;           // [NN,128] f32
  unsigned short* xb   = (unsigned short*)(he + (size_t)NN * 128);
  unsigned short* tbb  = xb   + (size_t)NN * DIM;       // [NN,768] bf16
  unsigned short* aggb = tbb  + (size_t)NN * 768;       // [NN,256] bf16
  unsigned short* attb = aggb + (size_t)NN * DIM;       // [NN,256] bf16
  unsigned short* VT   = attb + (size_t)NN * DIM;       // [256][NN] bf16
  unsigned short* xinb = VT   + (size_t)NN * DIM;       // [NN][96] bf16
  unsigned short* inwb = xinb + (size_t)NN * 96;        // [256][96] bf16
  unsigned short* warena = inwb + 256 * 96;             // WTOT bf16
  int* counts = (int*)(warena + WTOT);
  int* offs   = counts + NN;       // NN+1
  int* cursor = offs + NN + 1;
  int* esrc   = cursor + NN;       // NE
  float* po   = (float*)(esrc + NE);   // [S][NN][DIM] f32
  size_t used_f = (size_t)(po - ws);
  int S = 1;
  for (int cand = 4; cand >= 2; cand >>= 1) {
    size_t need = (used_f + (size_t)cand * NN * DIM + (size_t)cand * NN * NHEAD * 2) * 4;
    if (ws_size >= need) { S = cand; break; }
  }
  float* ml = po + (size_t)S * NN * DIM;
  int kspan = NN / S;

  const unsigned short* w_mlp1 = warena + WO0;
  const unsigned short* w_mlp2 = warena + WO1;
  const unsigned short* w_qkv  = warena + WO2;
  const unsigned short* w_aout = warena + WO3;
  const unsigned short* w_ffn1 = warena + WO4;
  const unsigned short* w_ffn2 = warena + WO5;
  const unsigned short* w_h1   = warena + WO6;

  // CSR build
  zero_counts<<<16, 256, 0, stream>>>(counts);
  count_edges<<<NE / 256, 256, 0, stream>>>(ei, counts);
  scan_offsets<<<1, 1024, 0, stream>>>(counts, offs, cursor);
  scatter_edges<<<NE / 256, 256, 0, stream>>>(ei, cursor, esrc);

  // weight + input conversions
  wconv<<<1312, 256, 0, stream>>>(mlp_w1, mlp_w2, attn_in_w, attn_out_w, ffn_w1, ffn_w2,
                                  head_w1, warena);
  pad72_96<<<(NN * 96 + 255) / 256, 256, 0, stream>>>(x_in, xinb, NN * 96);
  pad72_96<<<(256 * 96 + 255) / 256, 256, 0, stream>>>(in_w, inwb, 256 * 96);

  // input projection
  gemm_mfma<1,1,1,0><<<dim3(DIM/64, NN/64), 256, 0, stream>>>(xinb, inwb, in_b, x, xb,
                                                              NN, DIM, 96);

  for (int l = 0; l < 2; l++) {
    // GIN
    gin_agg<<<NN, 256, 0, stream>>>(offs, esrc, x, gin_eps, l, aggb);
    gemm_mfma<1,0,1,0><<<dim3(4, 64), 256, 0, stream>>>(aggb, w_mlp1 + (size_t)l*65536,
                                                        mlp_b1 + l*DIM, nullptr, tbb,
                                                        NN, DIM, DIM);
    gemm_mfma<0,1,0,0><<<dim3(4, 64), 256, 0, stream>>>(tbb, w_mlp2 + (size_t)l*65536,
                                                        mlp_b2 + l*DIM, t2, nullptr,
                                                        NN, DIM, DIM);
    ln_act_add<1><<<NN, 256, 0, stream>>>(t2, ln1_g + l*DIM, ln1_b + l*DIM, x, xb);

    // attention
    gemm_mfma<0,0,1,1><<<dim3(12, 64), 256, 0, stream>>>(xb, w_qkv + (size_t)l*196608,
                                                         attn_in_b + l*768, nullptr, tbb,
                                                         NN, 768, DIM);
    vt_transpose<<<dim3(32, 8), 256, 0, stream>>>(tbb, VT);
    attn_mfma_split<<<dim3(64, NHEAD, S), 256, 0, stream>>>(tbb, VT, po, ml, kspan);
    attn_merge<<<NN, 256, 0, stream>>>(po, ml, attb, S);
    gemm_mfma<0,1,0,0><<<dim3(4, 64), 256, 0, stream>>>(attb, w_aout + (size_t)l*65536,
                                                        attn_out_b + l*DIM, t2, nullptr,
                                                        NN, DIM, DIM);
    ln_act_add<0><<<NN, 256, 0, stream>>>(t2, ln2_g + l*DIM, ln2_b + l*DIM, x, xb);

    // FFN
    gemm_mfma<2,0,1,0><<<dim3(8, 64), 256, 0, stream>>>(xb, w_ffn1 + (size_t)l*131072,
                                                        ffn_b1 + l*512, nullptr, tbb,
                                                        NN, 512, DIM);
    gemm_mfma<0,1,0,0><<<dim3(4, 64), 256, 0, stream>>>(tbb, w_ffn2 + (size_t)l*131072,
                                                        ffn_b2 + l*DIM, t2, nullptr,
                                                        NN, DIM, 512);
    ln_act_add<0><<<NN, 256, 0, stream>>>(t2, ln3_g + l*DIM, ln3_b + l*DIM, x, xb);
  }

  // head
  gemm_mfma<1,1,0,0><<<dim3(2, 64), 256, 0, stream>>>(xb, w_h1, head_b1, he, nullptr,
                                                      NN, 128, DIM);
  head2_kernel<<<(NN * 5 + 255) / 256, 256, 0, stream>>>(he, head_w2, head_b2, (float*)d_out);
}